// Round 10
// baseline (132.261 us; speedup 1.0000x reference)
//
#include <hip/hip_runtime.h>
#include <hip/hip_bf16.h>

#define OBS_DIM 1024
#define ACT_DIM 8
#define HIDDEN  64
#define BATCH   131072
#define NBLOCKS (BATCH / 64)
#define KCHUNK  256                    // floats staged per chunk per row
#define NCHUNK  (OBS_DIM / KCHUNK)     // 4

typedef short bf16x8 __attribute__((ext_vector_type(8)));
typedef short bf16x4 __attribute__((ext_vector_type(4)));
typedef float f32x4  __attribute__((ext_vector_type(4)));

__device__ __forceinline__ ushort f2bf(float f) {
    union { __hip_bfloat16 h; ushort u; } c;
    c.h = __float2bfloat16(f);
    return c.u;
}

__device__ __forceinline__ float fast_tanh(float x) {
    float e = __expf(2.0f * x);
    return 1.0f - 2.0f / (e + 1.0f);
}

__device__ __forceinline__ bf16x8 pack8(float4 a, float4 b) {
    bf16x8 r;
    r[0] = (short)f2bf(a.x); r[1] = (short)f2bf(a.y);
    r[2] = (short)f2bf(a.z); r[3] = (short)f2bf(a.w);
    r[4] = (short)f2bf(b.x); r[5] = (short)f2bf(b.y);
    r[6] = (short)f2bf(b.z); r[7] = (short)f2bf(b.w);
    return r;
}

// tiny pre-kernel: w_in fp32 -> bf16 in workspace (65536 elems)
__global__ __launch_bounds__(256) void w_in_to_bf16(const float* __restrict__ w_in,
                                                    ushort* __restrict__ wbf) {
    const int i = (blockIdx.x * 256 + threadIdx.x) * 4;
    float4 v = *(const float4*)&w_in[i];
    ushort4 o;
    o.x = f2bf(v.x); o.y = f2bf(v.y); o.z = f2bf(v.z); o.w = f2bf(v.w);
    *(ushort4*)&wbf[i] = o;
}

// LDS: phase 1 stage[2][64][256] bf16 (64 KB, XOR-swizzled, 512B rows);
// phase 2 overlays x/z/wdq/wh (~30 KB) on the same block.
//
// Staging map: ONE wave load-instruction = ONE row's 1-KB chunk, fully
// contiguous (lane l covers bytes l*16..+16) — maximal DRAM burst locality.
// Wave w owns output cols [w*16, w*16+16) for ALL 64 rows; COMPUTE is
// vmem-free (A from LDS, B from regB prefetched pre-barrier), so FIFO waits
// never drain same-iteration obs loads. No sched_barriers needed.
template <bool USE_WS>
__global__ __launch_bounds__(256) void ac_mfma(
    const float* __restrict__ obs,  const float* __restrict__ w_in,
    const float* __restrict__ b_in, const float* __restrict__ w_h1,
    const float* __restrict__ b_h1, const float* __restrict__ w_pi,
    const float* __restrict__ b_pi, const float* __restrict__ w_v,
    const float* __restrict__ b_v,  const float* __restrict__ log_std,
    const ushort* __restrict__ wbf, float* __restrict__ out)
{
    __shared__ __align__(16) ushort smem[32768];

    const int tid = threadIdx.x;
    const int w   = tid >> 6;          // wave id
    const int l   = tid & 63;
    const int lr  = l & 15;
    const int lg  = l >> 4;
    const int row0 = blockIdx.x * 64;

    // B-fragment base for this wave's column strip (col = w*16 + lr)
    const size_t bbase = (size_t)(w * 16 + lr) * OBS_DIM + lg * 8;
    // obs base: wave w stages rows {i*4 + w}, lane l covers floats l*4..l*4+4
    const float* aptr = obs + (size_t)(row0 + w) * OBS_DIM + l * 4;

    float4 sv[16];
    bf16x8 regB[8];                    // one K-chunk of B (this wave's 16 cols)

#define LOADC(kc)                                                                  \
    _Pragma("unroll")                                                              \
    for (int i = 0; i < 16; ++i) {                                                 \
        sv[i] = *(const float4*)(aptr + (size_t)i * 4 * OBS_DIM + (kc) * KCHUNK);  \
    }

#define BLOAD(kc)                                                                  \
    _Pragma("unroll")                                                              \
    for (int s = 0; s < 8; ++s) {                                                  \
        if constexpr (USE_WS) {                                                    \
            regB[s] = *(const bf16x8*)(wbf + bbase + (kc) * KCHUNK + s * 32);      \
        } else {                                                                   \
            const float* bp = w_in + bbase + (kc) * KCHUNK + s * 32;               \
            regB[s] = pack8(*(const float4*)bp, *(const float4*)(bp + 4));         \
        }                                                                          \
    }

    // STOREC: row = i*4+w uniform per instr; 64 lanes write the row's full
    // 512 B contiguously (conflict-free); swizzle: ushort idx ^= (row&7)<<3
#define STOREC(kc)                                                                 \
    _Pragma("unroll")                                                              \
    for (int i = 0; i < 16; ++i) {                                                 \
        const int row = i * 4 + w;                                                 \
        bf16x4 v4;                                                                 \
        v4[0] = (short)f2bf(sv[i].x); v4[1] = (short)f2bf(sv[i].y);                \
        v4[2] = (short)f2bf(sv[i].z); v4[3] = (short)f2bf(sv[i].w);                \
        *(bf16x4*)&smem[((kc) & 1) * 16384 + row * 256 +                           \
                        ((l * 4) ^ ((row & 7) << 3))] = v4;                        \
    }

    // COMPUTE(kc): pure LDS + MFMA. 8 k-steps x 4 row-tiles = 32 MFMAs.
    // A row = rt*16+lr -> (row&7) == (lr&7): XOR is rt-independent.
#define COMPUTE(kc)                                                                \
    {                                                                              \
        const int bb = ((kc) & 1) * 16384;                                         \
        const int kswz = (lr & 7) << 3;                                            \
        _Pragma("unroll")                                                          \
        for (int s = 0; s < 8; ++s) {                                              \
            _Pragma("unroll")                                                      \
            for (int rt = 0; rt < 4; ++rt) {                                       \
                bf16x8 af = *(const bf16x8*)&smem[bb + (rt * 16 + lr) * 256 +      \
                                ((s * 32 + lg * 8) ^ kswz)];                       \
                acc[rt] = __builtin_amdgcn_mfma_f32_16x16x32_bf16(                 \
                              af, regB[s], acc[rt], 0, 0, 0);                      \
            }                                                                      \
        }                                                                          \
    }

    f32x4 acc[4];
    #pragma unroll
    for (int t = 0; t < 4; ++t) acc[t] = (f32x4){0.f, 0.f, 0.f, 0.f};

    // ---- layer 1 pipeline: 4 chunks, double-buffered LDS, 1 barrier/iter ----
    LOADC(0)
    BLOAD(0)
    STOREC(0)              // counted vmcnt: waits obs(0), B(0) stays in flight
    __syncthreads();
    #pragma unroll
    for (int kc = 0; kc < NCHUNK - 1; ++kc) {
        LOADC(kc + 1)      // obs prefetch (HBM): 16 x 1KB-contiguous wave-instrs
        COMPUTE(kc)        // waits B(kc) (pre-barrier FIFO) -> obs(kc+1) survives
        BLOAD(kc + 1)      // B prefetch (L2) for next iteration
        STOREC(kc + 1)     // waits obs(kc+1); B(kc+1) stays in flight
        __syncthreads();
    }
    COMPUTE(NCHUNK - 1)
    __syncthreads();       // stage buffers dead beyond this point

    ushort* x_lds = smem;               // [64][72]
    ushort* z_lds = smem + 4608;        // [64][72]
    ushort* wdq   = smem + 9216;        // [64][72]
    ushort* wh    = smem + 13824;       // [16][72]

    // x = tanh(acc + b_in) -> x_lds[row][h]; this wave wrote cols w*16+lr
    {
        const float b = b_in[w * 16 + lr];
        #pragma unroll
        for (int rt = 0; rt < 4; ++rt)
            #pragma unroll
            for (int r = 0; r < 4; ++r)
                x_lds[(rt * 16 + lg * 4 + r) * 72 + w * 16 + lr] =
                    f2bf(fast_tanh(acc[rt][r] + b));
    }

    // ---- NVFP4 fake-quant dequant of w_h1 -> wdq bf16 ----
    {
        const int o  = tid >> 2;
        const int hb = tid & 3;
        const float* wp = w_h1 + o * HIDDEN + hb * 16;
        float v[16];
        #pragma unroll
        for (int i = 0; i < 4; ++i) {
            float4 t4 = *(const float4*)(wp + i * 4);
            v[i*4+0] = t4.x; v[i*4+1] = t4.y; v[i*4+2] = t4.z; v[i*4+3] = t4.w;
        }
        float amax = 0.f;
        #pragma unroll
        for (int i = 0; i < 16; ++i) amax = fmaxf(amax, fabsf(v[i]));
        float scale = amax / 6.0f;
        if (scale == 0.f) scale = 1.f;
        #pragma unroll
        for (int i = 0; i < 16; ++i) {
            float xq = v[i] / scale;
            float ax = fabsf(xq);
            float q;
            if      (ax <= 0.25f) q = 0.0f;
            else if (ax <= 0.75f) q = 0.5f;
            else if (ax <= 1.25f) q = 1.0f;
            else if (ax <= 1.75f) q = 1.5f;
            else if (ax <= 2.5f)  q = 2.0f;
            else if (ax <= 3.5f)  q = 3.0f;
            else if (ax <= 5.0f)  q = 4.0f;
            else                  q = 6.0f;
            q = (xq < 0.f) ? -q : q;
            wdq[o * 72 + hb * 16 + i] = f2bf(q * scale);
        }
    }
    // head weights -> wh
    for (int t2 = tid; t2 < 16 * 64; t2 += 256) {
        const int o = t2 >> 6, h = t2 & 63;
        float val = (o < 8) ? w_pi[o * HIDDEN + h] : (o == 8 ? w_v[h] : 0.0f);
        wh[o * 72 + h] = f2bf(val);
    }
    __syncthreads();

    // ---- layer 2: z = tanh(x @ wdq^T + b_h1), K=64 (per-wave row strip) ----
    f32x4 acc2[4];
    #pragma unroll
    for (int t = 0; t < 4; ++t) acc2[t] = (f32x4){0.f, 0.f, 0.f, 0.f};
    #pragma unroll
    for (int ks = 0; ks < 2; ++ks) {
        bf16x8 af = *(const bf16x8*)&x_lds[(w * 16 + lr) * 72 + ks * 32 + lg * 8];
        #pragma unroll
        for (int t = 0; t < 4; ++t) {
            bf16x8 bfr = *(const bf16x8*)&wdq[(t * 16 + lr) * 72 + ks * 32 + lg * 8];
            acc2[t] = __builtin_amdgcn_mfma_f32_16x16x32_bf16(af, bfr, acc2[t], 0, 0, 0);
        }
    }
    #pragma unroll
    for (int t = 0; t < 4; ++t) {
        const float b = b_h1[t * 16 + lr];
        #pragma unroll
        for (int r = 0; r < 4; ++r)
            z_lds[(w * 16 + lg * 4 + r) * 72 + t * 16 + lr] = f2bf(fast_tanh(acc2[t][r] + b));
    }
    __syncthreads();

    // ---- heads as one 16-col MFMA tile (cols 0-7 mean, 8 value) ----
    f32x4 acc3 = (f32x4){0.f, 0.f, 0.f, 0.f};
    #pragma unroll
    for (int ks = 0; ks < 2; ++ks) {
        bf16x8 af  = *(const bf16x8*)&z_lds[(w * 16 + lr) * 72 + ks * 32 + lg * 8];
        bf16x8 bfr = *(const bf16x8*)&wh[lr * 72 + ks * 32 + lg * 8];
        acc3 = __builtin_amdgcn_mfma_f32_16x16x32_bf16(af, bfr, acc3, 0, 0, 0);
    }
    #pragma unroll
    for (int r = 0; r < 4; ++r) {
        const int row = row0 + w * 16 + lg * 4 + r;
        if (lr < 8)
            out[(size_t)row * 8 + lr] = acc3[r] + b_pi[lr];
        else if (lr == 8)
            out[(size_t)2 * BATCH * 8 + row] = acc3[r] + b_v[0];
    }

    // ---- std broadcast ----
    {
        const int idx = tid * 2;
        const int rl = idx >> 3, a = idx & 7;
        float2 s;
        s.x = __expf(log_std[a]);
        s.y = __expf(log_std[a + 1]);
        *(float2*)&out[(size_t)BATCH * 8 + (size_t)(row0 + rl) * 8 + a] = s;
    }
#undef LOADC
#undef BLOAD
#undef STOREC
#undef COMPUTE
}

extern "C" void kernel_launch(void* const* d_in, const int* in_sizes, int n_in,
                              void* d_out, int out_size, void* d_ws, size_t ws_size,
                              hipStream_t stream) {
    (void)in_sizes; (void)n_in; (void)out_size;
    const float* obs   = (const float*)d_in[0];
    const float* w_in  = (const float*)d_in[1];
    const float* b_in  = (const float*)d_in[2];
    const float* w_h1  = (const float*)d_in[3];
    const float* b_h1  = (const float*)d_in[4];
    const float* w_pi  = (const float*)d_in[5];
    const float* b_pi  = (const float*)d_in[6];
    const float* w_v   = (const float*)d_in[7];
    const float* b_v   = (const float*)d_in[8];
    const float* lstd  = (const float*)d_in[9];
    float* out = (float*)d_out;

    const size_t wbf_bytes = (size_t)HIDDEN * OBS_DIM * sizeof(ushort);
    if (ws_size >= wbf_bytes) {
        ushort* wbf = (ushort*)d_ws;
        hipLaunchKernelGGL(w_in_to_bf16, dim3(HIDDEN * OBS_DIM / 1024), dim3(256), 0, stream,
                           w_in, wbf);
        hipLaunchKernelGGL((ac_mfma<true>), dim3(NBLOCKS), dim3(256), 0, stream,
                           obs, w_in, b_in, w_h1, b_h1, w_pi, b_pi, w_v, b_v, lstd,
                           wbf, out);
    } else {
        hipLaunchKernelGGL((ac_mfma<false>), dim3(NBLOCKS), dim3(256), 0, stream,
                           obs, w_in, b_in, w_h1, b_h1, w_pi, b_pi, w_v, b_v, lstd,
                           (const ushort*)nullptr, out);
    }
}

// Round 11
// 124.062 us; speedup vs baseline: 1.0661x; 1.0661x over previous
//
#include <hip/hip_runtime.h>
#include <hip/hip_bf16.h>

#define OBS_DIM 1024
#define ACT_DIM 8
#define HIDDEN  64
#define BATCH   131072
#define NBLOCKS (BATCH / 64)
#define KCHUNK  128                    // floats staged per chunk per row
#define NCHUNK  (OBS_DIM / KCHUNK)     // 8

typedef short bf16x8 __attribute__((ext_vector_type(8)));
typedef short bf16x4 __attribute__((ext_vector_type(4)));
typedef float f32x4  __attribute__((ext_vector_type(4)));

__device__ __forceinline__ ushort f2bf(float f) {
    union { __hip_bfloat16 h; ushort u; } c;
    c.h = __float2bfloat16(f);
    return c.u;
}

__device__ __forceinline__ float fast_tanh(float x) {
    float e = __expf(2.0f * x);
    return 1.0f - 2.0f / (e + 1.0f);
}

__device__ __forceinline__ bf16x8 pack8(float4 a, float4 b) {
    bf16x8 r;
    r[0] = (short)f2bf(a.x); r[1] = (short)f2bf(a.y);
    r[2] = (short)f2bf(a.z); r[3] = (short)f2bf(a.w);
    r[4] = (short)f2bf(b.x); r[5] = (short)f2bf(b.y);
    r[6] = (short)f2bf(b.z); r[7] = (short)f2bf(b.w);
    return r;
}

// Single-kernel version (no pre-kernel): B fragments converted fp32->bf16
// inline in BLOAD. w_in (256 KB) is L2/L3-resident; off the HBM critical path.
//
// LDS: phase 1 stage[2][64][128] bf16 (32 KB, XOR-swizzled at 16B-slot
// granularity); phase 2 overlays x/z/wdq/wh on the same 32 KB.
// Decomposition: wave w owns output cols [w*16, w*16+16) for ALL 64 rows.
// COMPUTE is vmem-free; obs prefetch 2 chunks deep; FIFO discipline: B(kc)
// issued BEFORE obs(kc+1) so B-waits never drain fresh HBM loads.
__global__ __launch_bounds__(256, 3) void ac_mfma(
    const float* __restrict__ obs,  const float* __restrict__ w_in,
    const float* __restrict__ b_in, const float* __restrict__ w_h1,
    const float* __restrict__ b_h1, const float* __restrict__ w_pi,
    const float* __restrict__ b_pi, const float* __restrict__ w_v,
    const float* __restrict__ b_v,  const float* __restrict__ log_std,
    float* __restrict__ out)
{
    __shared__ __align__(16) ushort smem[16384];

    const int tid = threadIdx.x;
    const int w   = tid >> 6;
    const int l   = tid & 63;
    const int lr  = l & 15;
    const int lg  = l >> 4;
    const int row0 = blockIdx.x * 64;

    // staging map: 32 consecutive lanes cover one row's 512B chunk contiguously
    const int srow = tid >> 5;            // 0..7
    const int scol = (tid & 31) * 4;
    const int sswz = srow << 3;           // XOR swizzle in elems (16B slots)

    // B-fragment base for this wave's column strip (col = w*16 + lr)
    const size_t bbase = (size_t)(w * 16 + lr) * OBS_DIM + lg * 8;

    float4 svA[8], svB[8];
    bf16x8 regB[2][4];                    // [parity][s]; fully unrolled -> static idx

#define LOADC(kc, sv)                                                              \
    _Pragma("unroll")                                                              \
    for (int i = 0; i < 8; ++i) {                                                  \
        const int row = i * 8 + srow;                                              \
        sv[i] = *(const float4*)&obs[(size_t)(row0 + row) * OBS_DIM +              \
                                     (kc) * KCHUNK + scol];                        \
    }

#define BLOAD(kc)                                                                  \
    _Pragma("unroll")                                                              \
    for (int s = 0; s < 4; ++s) {                                                  \
        const float* bp = w_in + bbase + ((kc) * 4 + s) * 32;                      \
        regB[(kc) & 1][s] = pack8(*(const float4*)bp, *(const float4*)(bp + 4));   \
    }

#define STOREC(kc, sv)                                                             \
    _Pragma("unroll")                                                              \
    for (int i = 0; i < 8; ++i) {                                                  \
        const int row = i * 8 + srow;                                              \
        bf16x4 v4;                                                                 \
        v4[0] = (short)f2bf(sv[i].x); v4[1] = (short)f2bf(sv[i].y);                \
        v4[2] = (short)f2bf(sv[i].z); v4[3] = (short)f2bf(sv[i].w);                \
        *(bf16x4*)&smem[((kc) & 1) * 8192 + row * 128 + (scol ^ sswz)] = v4;       \
    }

    // COMPUTE(kc): pure LDS + MFMA. A row-tiles rt=0..3 (rows rt*16+lr),
    // B from regB[kc&1] (this wave's 16 cols).
#define COMPUTE(kc)                                                                \
    {                                                                              \
        const int bb = ((kc) & 1) * 8192;                                          \
        _Pragma("unroll")                                                          \
        for (int s = 0; s < 4; ++s) {                                              \
            _Pragma("unroll")                                                      \
            for (int rt = 0; rt < 4; ++rt) {                                       \
                const int arow = rt * 16 + lr;                                     \
                bf16x8 af = *(const bf16x8*)&smem[bb + arow * 128 +                \
                                ((s * 32 + lg * 8) ^ ((arow & 7) << 3))];          \
                acc[rt] = __builtin_amdgcn_mfma_f32_16x16x32_bf16(                 \
                              af, regB[(kc) & 1][s], acc[rt], 0, 0, 0);            \
            }                                                                      \
        }                                                                          \
    }

// pin vmem issue order (B before next obs) without blocking VALU/SALU/DS motion
#define VMEM_FENCE() __builtin_amdgcn_sched_barrier(0x106)

    f32x4 acc[4];
    #pragma unroll
    for (int t = 0; t < 4; ++t) acc[t] = (f32x4){0.f, 0.f, 0.f, 0.f};

    // ---- layer 1 pipeline: 2-deep obs prefetch, vmem-free COMPUTE ----
    BLOAD(0)
    LOADC(0, svA)
    LOADC(1, svB)
    STOREC(0, svA)          // counted vmcnt: obs(1) stays in flight
    __syncthreads();
    for (int kc = 1; kc < NCHUNK - 1; kc += 2) {    // kc = 1, 3, 5
        BLOAD(kc)
        VMEM_FENCE();
        LOADC(kc + 1, svA)                           // 2-ahead obs prefetch
        COMPUTE(kc - 1)                              // waits B(kc-1): long done
        STOREC(kc, svB)                              // waits obs(kc): ~1.5 iters old
        __syncthreads();
        BLOAD(kc + 1)
        VMEM_FENCE();
        LOADC(kc + 2, svB)
        COMPUTE(kc)
        STOREC(kc + 1, svA)
        __syncthreads();
    }
    BLOAD(NCHUNK - 1)
    COMPUTE(NCHUNK - 2)
    STOREC(NCHUNK - 1, svB)
    __syncthreads();
    COMPUTE(NCHUNK - 1)
    __syncthreads();       // stage buffers dead beyond this point

    ushort* x_lds = smem;               // [64][72]
    ushort* z_lds = smem + 4608;        // [64][72]
    ushort* wdq   = smem + 9216;        // [64][72]
    ushort* wh    = smem + 13824;       // [16][72]

    // x = tanh(acc + b_in) -> x_lds[row][h]; this wave wrote cols w*16+lr
    {
        const float b = b_in[w * 16 + lr];
        #pragma unroll
        for (int rt = 0; rt < 4; ++rt)
            #pragma unroll
            for (int r = 0; r < 4; ++r)
                x_lds[(rt * 16 + lg * 4 + r) * 72 + w * 16 + lr] =
                    f2bf(fast_tanh(acc[rt][r] + b));
    }

    // ---- NVFP4 fake-quant dequant of w_h1 -> wdq bf16 ----
    {
        const int o  = tid >> 2;
        const int hb = tid & 3;
        const float* wp = w_h1 + o * HIDDEN + hb * 16;
        float v[16];
        #pragma unroll
        for (int i = 0; i < 4; ++i) {
            float4 t4 = *(const float4*)(wp + i * 4);
            v[i*4+0] = t4.x; v[i*4+1] = t4.y; v[i*4+2] = t4.z; v[i*4+3] = t4.w;
        }
        float amax = 0.f;
        #pragma unroll
        for (int i = 0; i < 16; ++i) amax = fmaxf(amax, fabsf(v[i]));
        float scale = amax / 6.0f;
        if (scale == 0.f) scale = 1.f;
        #pragma unroll
        for (int i = 0; i < 16; ++i) {
            float xq = v[i] / scale;
            float ax = fabsf(xq);
            float q;
            if      (ax <= 0.25f) q = 0.0f;
            else if (ax <= 0.75f) q = 0.5f;
            else if (ax <= 1.25f) q = 1.0f;
            else if (ax <= 1.75f) q = 1.5f;
            else if (ax <= 2.5f)  q = 2.0f;
            else if (ax <= 3.5f)  q = 3.0f;
            else if (ax <= 5.0f)  q = 4.0f;
            else                  q = 6.0f;
            q = (xq < 0.f) ? -q : q;
            wdq[o * 72 + hb * 16 + i] = f2bf(q * scale);
        }
    }
    // head weights -> wh
    for (int t2 = tid; t2 < 16 * 64; t2 += 256) {
        const int o = t2 >> 6, h = t2 & 63;
        float val = (o < 8) ? w_pi[o * HIDDEN + h] : (o == 8 ? w_v[h] : 0.0f);
        wh[o * 72 + h] = f2bf(val);
    }
    __syncthreads();

    // ---- layer 2: z = tanh(x @ wdq^T + b_h1), K=64 (per-wave row strip) ----
    f32x4 acc2[4];
    #pragma unroll
    for (int t = 0; t < 4; ++t) acc2[t] = (f32x4){0.f, 0.f, 0.f, 0.f};
    #pragma unroll
    for (int ks = 0; ks < 2; ++ks) {
        bf16x8 af = *(const bf16x8*)&x_lds[(w * 16 + lr) * 72 + ks * 32 + lg * 8];
        #pragma unroll
        for (int t = 0; t < 4; ++t) {
            bf16x8 bfr = *(const bf16x8*)&wdq[(t * 16 + lr) * 72 + ks * 32 + lg * 8];
            acc2[t] = __builtin_amdgcn_mfma_f32_16x16x32_bf16(af, bfr, acc2[t], 0, 0, 0);
        }
    }
    #pragma unroll
    for (int t = 0; t < 4; ++t) {
        const float b = b_h1[t * 16 + lr];
        #pragma unroll
        for (int r = 0; r < 4; ++r)
            z_lds[(w * 16 + lg * 4 + r) * 72 + t * 16 + lr] = f2bf(fast_tanh(acc2[t][r] + b));
    }
    __syncthreads();

    // ---- heads as one 16-col MFMA tile (cols 0-7 mean, 8 value) ----
    f32x4 acc3 = (f32x4){0.f, 0.f, 0.f, 0.f};
    #pragma unroll
    for (int ks = 0; ks < 2; ++ks) {
        bf16x8 af  = *(const bf16x8*)&z_lds[(w * 16 + lr) * 72 + ks * 32 + lg * 8];
        bf16x8 bfr = *(const bf16x8*)&wh[lr * 72 + ks * 32 + lg * 8];
        acc3 = __builtin_amdgcn_mfma_f32_16x16x32_bf16(af, bfr, acc3, 0, 0, 0);
    }
    #pragma unroll
    for (int r = 0; r < 4; ++r) {
        const int row = row0 + w * 16 + lg * 4 + r;
        if (lr < 8)
            out[(size_t)row * 8 + lr] = acc3[r] + b_pi[lr];
        else if (lr == 8)
            out[(size_t)2 * BATCH * 8 + row] = acc3[r] + b_v[0];
    }

    // ---- std broadcast ----
    {
        const int idx = tid * 2;
        const int rl = idx >> 3, a = idx & 7;
        float2 s;
        s.x = __expf(log_std[a]);
        s.y = __expf(log_std[a + 1]);
        *(float2*)&out[(size_t)BATCH * 8 + (size_t)(row0 + rl) * 8 + a] = s;
    }
#undef LOADC
#undef BLOAD
#undef STOREC
#undef COMPUTE
#undef VMEM_FENCE
}

extern "C" void kernel_launch(void* const* d_in, const int* in_sizes, int n_in,
                              void* d_out, int out_size, void* d_ws, size_t ws_size,
                              hipStream_t stream) {
    (void)in_sizes; (void)n_in; (void)out_size; (void)d_ws; (void)ws_size;
    const float* obs   = (const float*)d_in[0];
    const float* w_in  = (const float*)d_in[1];
    const float* b_in  = (const float*)d_in[2];
    const float* w_h1  = (const float*)d_in[3];
    const float* b_h1  = (const float*)d_in[4];
    const float* w_pi  = (const float*)d_in[5];
    const float* b_pi  = (const float*)d_in[6];
    const float* w_v   = (const float*)d_in[7];
    const float* b_v   = (const float*)d_in[8];
    const float* lstd  = (const float*)d_in[9];
    float* out = (float*)d_out;

    hipLaunchKernelGGL(ac_mfma, dim3(NBLOCKS), dim3(256), 0, stream,
                       obs, w_in, b_in, w_h1, b_h1, w_pi, b_pi, w_v, b_v, lstd, out);
}

// Round 12
// 103.405 us; speedup vs baseline: 1.2791x; 1.1998x over previous
//
#include <hip/hip_runtime.h>
#include <hip/hip_bf16.h>

#define OBS_DIM 1024
#define ACT_DIM 8
#define HIDDEN  64
#define BATCH   131072
#define NBLOCKS (BATCH / 64)
#define KCHUNK  128                    // floats staged per chunk per row
#define NCHUNK  (OBS_DIM / KCHUNK)     // 8

typedef short bf16x8 __attribute__((ext_vector_type(8)));
typedef short bf16x4 __attribute__((ext_vector_type(4)));
typedef float f32x4  __attribute__((ext_vector_type(4)));
typedef float fx4    __attribute__((ext_vector_type(4)));   // native vec for nt loads

__device__ __forceinline__ ushort f2bf(float f) {
    union { __hip_bfloat16 h; ushort u; } c;
    c.h = __float2bfloat16(f);
    return c.u;
}

__device__ __forceinline__ float fast_tanh(float x) {
    float e = __expf(2.0f * x);
    return 1.0f - 2.0f / (e + 1.0f);
}

__device__ __forceinline__ bf16x8 pack8(float4 a, float4 b) {
    bf16x8 r;
    r[0] = (short)f2bf(a.x); r[1] = (short)f2bf(a.y);
    r[2] = (short)f2bf(a.z); r[3] = (short)f2bf(a.w);
    r[4] = (short)f2bf(b.x); r[5] = (short)f2bf(b.y);
    r[6] = (short)f2bf(b.z); r[7] = (short)f2bf(b.w);
    return r;
}

// tiny pre-kernel: w_in fp32 -> bf16 in workspace (65536 elems)
__global__ __launch_bounds__(256) void w_in_to_bf16(const float* __restrict__ w_in,
                                                    ushort* __restrict__ wbf) {
    const int i = (blockIdx.x * 256 + threadIdx.x) * 4;
    float4 v = *(const float4*)&w_in[i];
    ushort4 o;
    o.x = f2bf(v.x); o.y = f2bf(v.y); o.z = f2bf(v.z); o.w = f2bf(v.w);
    *(ushort4*)&wbf[i] = o;
}

// R7 structure (best measured: 112.7 us) + non-temporal obs loads.
// LDS: phase 1 stage[2][64][128] bf16 (32 KB, XOR-swizzled at 16B-slot
// granularity); phase 2 overlays x/z/wdq/wh on the same 32 KB.
// Decomposition: wave w owns output cols [w*16, w*16+16) for ALL 64 rows.
// COMPUTE is vmem-free; obs prefetch 2 chunks deep; FIFO discipline: B(kc)
// issued BEFORE obs(kc+1) so B-waits never drain fresh HBM loads.
// obs is read-once (512 MB): nt hint skips cache allocation on the stream.
template <bool USE_WS>
__global__ __launch_bounds__(256) void ac_mfma(
    const float* __restrict__ obs,  const float* __restrict__ w_in,
    const float* __restrict__ b_in, const float* __restrict__ w_h1,
    const float* __restrict__ b_h1, const float* __restrict__ w_pi,
    const float* __restrict__ b_pi, const float* __restrict__ w_v,
    const float* __restrict__ b_v,  const float* __restrict__ log_std,
    const ushort* __restrict__ wbf, float* __restrict__ out)
{
    __shared__ __align__(16) ushort smem[16384];

    const int tid = threadIdx.x;
    const int w   = tid >> 6;
    const int l   = tid & 63;
    const int lr  = l & 15;
    const int lg  = l >> 4;
    const int row0 = blockIdx.x * 64;

    // staging map: 32 consecutive lanes cover one row's 512B chunk contiguously
    const int srow = tid >> 5;            // 0..7
    const int scol = (tid & 31) * 4;
    const int sswz = srow << 3;           // XOR swizzle in elems (16B slots)

    // B-fragment base for this wave's column strip (col = w*16 + lr)
    const size_t bbase = (size_t)(w * 16 + lr) * OBS_DIM + lg * 8;

    fx4 svA[8], svB[8];
    bf16x8 regB[2][4];                    // [parity][s]; fully unrolled -> static idx

#define LOADC(kc, sv)                                                              \
    _Pragma("unroll")                                                              \
    for (int i = 0; i < 8; ++i) {                                                  \
        const int row = i * 8 + srow;                                              \
        sv[i] = __builtin_nontemporal_load(                                        \
            (const fx4*)&obs[(size_t)(row0 + row) * OBS_DIM + (kc) * KCHUNK +      \
                             scol]);                                               \
    }

#define BLOAD(kc)                                                                  \
    _Pragma("unroll")                                                              \
    for (int s = 0; s < 4; ++s) {                                                  \
        if constexpr (USE_WS) {                                                    \
            regB[(kc) & 1][s] = *(const bf16x8*)(wbf + bbase +                     \
                                                 ((kc) * 4 + s) * 32);             \
        } else {                                                                   \
            const float* bp = w_in + bbase + ((kc) * 4 + s) * 32;                  \
            regB[(kc) & 1][s] = pack8(*(const float4*)bp, *(const float4*)(bp+4)); \
        }                                                                          \
    }

#define STOREC(kc, sv)                                                             \
    _Pragma("unroll")                                                              \
    for (int i = 0; i < 8; ++i) {                                                  \
        const int row = i * 8 + srow;                                              \
        bf16x4 v4;                                                                 \
        v4[0] = (short)f2bf(sv[i][0]); v4[1] = (short)f2bf(sv[i][1]);              \
        v4[2] = (short)f2bf(sv[i][2]); v4[3] = (short)f2bf(sv[i][3]);              \
        *(bf16x4*)&smem[((kc) & 1) * 8192 + row * 128 + (scol ^ sswz)] = v4;       \
    }

    // COMPUTE(kc): pure LDS + MFMA. A row-tiles rt=0..3 (rows rt*16+lr),
    // B from regB[kc&1] (this wave's 16 cols).
#define COMPUTE(kc)                                                                \
    {                                                                              \
        const int bb = ((kc) & 1) * 8192;                                          \
        _Pragma("unroll")                                                          \
        for (int s = 0; s < 4; ++s) {                                              \
            _Pragma("unroll")                                                      \
            for (int rt = 0; rt < 4; ++rt) {                                       \
                const int arow = rt * 16 + lr;                                     \
                bf16x8 af = *(const bf16x8*)&smem[bb + arow * 128 +                \
                                ((s * 32 + lg * 8) ^ ((arow & 7) << 3))];          \
                acc[rt] = __builtin_amdgcn_mfma_f32_16x16x32_bf16(                 \
                              af, regB[(kc) & 1][s], acc[rt], 0, 0, 0);            \
            }                                                                      \
        }                                                                          \
    }

// pin vmem issue order (B before next obs) without blocking VALU/SALU/DS motion
#define VMEM_FENCE() __builtin_amdgcn_sched_barrier(0x106)

    f32x4 acc[4];
    #pragma unroll
    for (int t = 0; t < 4; ++t) acc[t] = (f32x4){0.f, 0.f, 0.f, 0.f};

    // ---- layer 1 pipeline: 2-deep obs prefetch, vmem-free COMPUTE ----
    BLOAD(0)
    LOADC(0, svA)
    LOADC(1, svB)
    STOREC(0, svA)          // counted vmcnt: obs(1) stays in flight
    __syncthreads();
    for (int kc = 1; kc < NCHUNK - 1; kc += 2) {    // kc = 1, 3, 5
        BLOAD(kc)
        VMEM_FENCE();
        LOADC(kc + 1, svA)                           // 2-ahead obs prefetch
        COMPUTE(kc - 1)                              // waits B(kc-1): long done
        STOREC(kc, svB)                              // waits obs(kc): ~1.5 iters old
        __syncthreads();
        BLOAD(kc + 1)
        VMEM_FENCE();
        LOADC(kc + 2, svB)
        COMPUTE(kc)
        STOREC(kc + 1, svA)
        __syncthreads();
    }
    BLOAD(NCHUNK - 1)
    COMPUTE(NCHUNK - 2)
    STOREC(NCHUNK - 1, svB)
    __syncthreads();
    COMPUTE(NCHUNK - 1)
    __syncthreads();       // stage buffers dead beyond this point

    ushort* x_lds = smem;               // [64][72]
    ushort* z_lds = smem + 4608;        // [64][72]
    ushort* wdq   = smem + 9216;        // [64][72]
    ushort* wh    = smem + 13824;       // [16][72]

    // x = tanh(acc + b_in) -> x_lds[row][h]; this wave wrote cols w*16+lr
    {
        const float b = b_in[w * 16 + lr];
        #pragma unroll
        for (int rt = 0; rt < 4; ++rt)
            #pragma unroll
            for (int r = 0; r < 4; ++r)
                x_lds[(rt * 16 + lg * 4 + r) * 72 + w * 16 + lr] =
                    f2bf(fast_tanh(acc[rt][r] + b));
    }

    // ---- NVFP4 fake-quant dequant of w_h1 -> wdq bf16 ----
    {
        const int o  = tid >> 2;
        const int hb = tid & 3;
        const float* wp = w_h1 + o * HIDDEN + hb * 16;
        float v[16];
        #pragma unroll
        for (int i = 0; i < 4; ++i) {
            float4 t4 = *(const float4*)(wp + i * 4);
            v[i*4+0] = t4.x; v[i*4+1] = t4.y; v[i*4+2] = t4.z; v[i*4+3] = t4.w;
        }
        float amax = 0.f;
        #pragma unroll
        for (int i = 0; i < 16; ++i) amax = fmaxf(amax, fabsf(v[i]));
        float scale = amax / 6.0f;
        if (scale == 0.f) scale = 1.f;
        #pragma unroll
        for (int i = 0; i < 16; ++i) {
            float xq = v[i] / scale;
            float ax = fabsf(xq);
            float q;
            if      (ax <= 0.25f) q = 0.0f;
            else if (ax <= 0.75f) q = 0.5f;
            else if (ax <= 1.25f) q = 1.0f;
            else if (ax <= 1.75f) q = 1.5f;
            else if (ax <= 2.5f)  q = 2.0f;
            else if (ax <= 3.5f)  q = 3.0f;
            else if (ax <= 5.0f)  q = 4.0f;
            else                  q = 6.0f;
            q = (xq < 0.f) ? -q : q;
            wdq[o * 72 + hb * 16 + i] = f2bf(q * scale);
        }
    }
    // head weights -> wh
    for (int t2 = tid; t2 < 16 * 64; t2 += 256) {
        const int o = t2 >> 6, h = t2 & 63;
        float val = (o < 8) ? w_pi[o * HIDDEN + h] : (o == 8 ? w_v[h] : 0.0f);
        wh[o * 72 + h] = f2bf(val);
    }
    __syncthreads();

    // ---- layer 2: z = tanh(x @ wdq^T + b_h1), K=64 (per-wave row strip) ----
    f32x4 acc2[4];
    #pragma unroll
    for (int t = 0; t < 4; ++t) acc2[t] = (f32x4){0.f, 0.f, 0.f, 0.f};
    #pragma unroll
    for (int ks = 0; ks < 2; ++ks) {
        bf16x8 af = *(const bf16x8*)&x_lds[(w * 16 + lr) * 72 + ks * 32 + lg * 8];
        #pragma unroll
        for (int t = 0; t < 4; ++t) {
            bf16x8 bfr = *(const bf16x8*)&wdq[(t * 16 + lr) * 72 + ks * 32 + lg * 8];
            acc2[t] = __builtin_amdgcn_mfma_f32_16x16x32_bf16(af, bfr, acc2[t], 0, 0, 0);
        }
    }
    #pragma unroll
    for (int t = 0; t < 4; ++t) {
        const float b = b_h1[t * 16 + lr];
        #pragma unroll
        for (int r = 0; r < 4; ++r)
            z_lds[(w * 16 + lg * 4 + r) * 72 + t * 16 + lr] = f2bf(fast_tanh(acc2[t][r] + b));
    }
    __syncthreads();

    // ---- heads as one 16-col MFMA tile (cols 0-7 mean, 8 value) ----
    f32x4 acc3 = (f32x4){0.f, 0.f, 0.f, 0.f};
    #pragma unroll
    for (int ks = 0; ks < 2; ++ks) {
        bf16x8 af  = *(const bf16x8*)&z_lds[(w * 16 + lr) * 72 + ks * 32 + lg * 8];
        bf16x8 bfr = *(const bf16x8*)&wh[lr * 72 + ks * 32 + lg * 8];
        acc3 = __builtin_amdgcn_mfma_f32_16x16x32_bf16(af, bfr, acc3, 0, 0, 0);
    }
    #pragma unroll
    for (int r = 0; r < 4; ++r) {
        const int row = row0 + w * 16 + lg * 4 + r;
        if (lr < 8)
            out[(size_t)row * 8 + lr] = acc3[r] + b_pi[lr];
        else if (lr == 8)
            out[(size_t)2 * BATCH * 8 + row] = acc3[r] + b_v[0];
    }

    // ---- std broadcast ----
    {
        const int idx = tid * 2;
        const int rl = idx >> 3, a = idx & 7;
        float2 s;
        s.x = __expf(log_std[a]);
        s.y = __expf(log_std[a + 1]);
        *(float2*)&out[(size_t)BATCH * 8 + (size_t)(row0 + rl) * 8 + a] = s;
    }
#undef LOADC
#undef BLOAD
#undef STOREC
#undef COMPUTE
#undef VMEM_FENCE
}

extern "C" void kernel_launch(void* const* d_in, const int* in_sizes, int n_in,
                              void* d_out, int out_size, void* d_ws, size_t ws_size,
                              hipStream_t stream) {
    (void)in_sizes; (void)n_in; (void)out_size;
    const float* obs   = (const float*)d_in[0];
    const float* w_in  = (const float*)d_in[1];
    const float* b_in  = (const float*)d_in[2];
    const float* w_h1  = (const float*)d_in[3];
    const float* b_h1  = (const float*)d_in[4];
    const float* w_pi  = (const float*)d_in[5];
    const float* b_pi  = (const float*)d_in[6];
    const float* w_v   = (const float*)d_in[7];
    const float* b_v   = (const float*)d_in[8];
    const float* lstd  = (const float*)d_in[9];
    float* out = (float*)d_out;

    const size_t wbf_bytes = (size_t)HIDDEN * OBS_DIM * sizeof(ushort);
    if (ws_size >= wbf_bytes) {
        ushort* wbf = (ushort*)d_ws;
        hipLaunchKernelGGL(w_in_to_bf16, dim3(HIDDEN * OBS_DIM / 1024), dim3(256), 0, stream,
                           w_in, wbf);
        hipLaunchKernelGGL((ac_mfma<true>), dim3(NBLOCKS), dim3(256), 0, stream,
                           obs, w_in, b_in, w_h1, b_h1, w_pi, b_pi, w_v, b_v, lstd,
                           wbf, out);
    } else {
        hipLaunchKernelGGL((ac_mfma<false>), dim3(NBLOCKS), dim3(256), 0, stream,
                           obs, w_in, b_in, w_h1, b_h1, w_pi, b_pi, w_v, b_v, lstd,
                           (const ushort*)nullptr, out);
    }
}

// Round 13
// 103.015 us; speedup vs baseline: 1.2839x; 1.0038x over previous
//
#include <hip/hip_runtime.h>
#include <hip/hip_bf16.h>

#define OBS_DIM 1024
#define ACT_DIM 8
#define HIDDEN  64
#define BATCH   131072
#define NBLOCKS (BATCH / 64)
#define KCHUNK  128                    // floats staged per chunk per row
#define NCHUNK  (OBS_DIM / KCHUNK)     // 8

typedef short bf16x8 __attribute__((ext_vector_type(8)));
typedef short bf16x4 __attribute__((ext_vector_type(4)));
typedef float f32x4  __attribute__((ext_vector_type(4)));
typedef float fx4    __attribute__((ext_vector_type(4)));   // native vec for nt loads

__device__ __forceinline__ ushort f2bf(float f) {
    union { __hip_bfloat16 h; ushort u; } c;
    c.h = __float2bfloat16(f);
    return c.u;
}

__device__ __forceinline__ float fast_tanh(float x) {
    float e = __expf(2.0f * x);
    return 1.0f - 2.0f / (e + 1.0f);
}

__device__ __forceinline__ bf16x8 pack8(float4 a, float4 b) {
    bf16x8 r;
    r[0] = (short)f2bf(a.x); r[1] = (short)f2bf(a.y);
    r[2] = (short)f2bf(a.z); r[3] = (short)f2bf(a.w);
    r[4] = (short)f2bf(b.x); r[5] = (short)f2bf(b.y);
    r[6] = (short)f2bf(b.z); r[7] = (short)f2bf(b.w);
    return r;
}

// tiny pre-kernel: w_in fp32 -> bf16 in workspace (65536 elems)
__global__ __launch_bounds__(256) void w_in_to_bf16(const float* __restrict__ w_in,
                                                    ushort* __restrict__ wbf) {
    const int i = (blockIdx.x * 256 + threadIdx.x) * 4;
    float4 v = *(const float4*)&w_in[i];
    ushort4 o;
    o.x = f2bf(v.x); o.y = f2bf(v.y); o.z = f2bf(v.z); o.w = f2bf(v.w);
    *(ushort4*)&wbf[i] = o;
}

// R12 structure (best measured: 103.4 us = nt obs loads) + lgkm-only in-loop
// barrier: with nt every obs load is a full HBM round trip, so the
// __syncthreads vmcnt(0) drain per chunk iteration may now be the binding
// stall (it was null pre-nt when cache-fill overhead dominated).
template <bool USE_WS>
__global__ __launch_bounds__(256) void ac_mfma(
    const float* __restrict__ obs,  const float* __restrict__ w_in,
    const float* __restrict__ b_in, const float* __restrict__ w_h1,
    const float* __restrict__ b_h1, const float* __restrict__ w_pi,
    const float* __restrict__ b_pi, const float* __restrict__ w_v,
    const float* __restrict__ b_v,  const float* __restrict__ log_std,
    const ushort* __restrict__ wbf, float* __restrict__ out)
{
    __shared__ __align__(16) ushort smem[16384];

    const int tid = threadIdx.x;
    const int w   = tid >> 6;
    const int l   = tid & 63;
    const int lr  = l & 15;
    const int lg  = l >> 4;
    const int row0 = blockIdx.x * 64;

    // staging map: 32 consecutive lanes cover one row's 512B chunk contiguously
    const int srow = tid >> 5;            // 0..7
    const int scol = (tid & 31) * 4;
    const int sswz = srow << 3;           // XOR swizzle in elems (16B slots)

    // B-fragment base for this wave's column strip (col = w*16 + lr)
    const size_t bbase = (size_t)(w * 16 + lr) * OBS_DIM + lg * 8;

    fx4 svA[8], svB[8];
    bf16x8 regB[2][4];                    // [parity][s]; fully unrolled -> static idx

#define LOADC(kc, sv)                                                              \
    _Pragma("unroll")                                                              \
    for (int i = 0; i < 8; ++i) {                                                  \
        const int row = i * 8 + srow;                                              \
        sv[i] = __builtin_nontemporal_load(                                        \
            (const fx4*)&obs[(size_t)(row0 + row) * OBS_DIM + (kc) * KCHUNK +      \
                             scol]);                                               \
    }

#define BLOAD(kc)                                                                  \
    _Pragma("unroll")                                                              \
    for (int s = 0; s < 4; ++s) {                                                  \
        if constexpr (USE_WS) {                                                    \
            regB[(kc) & 1][s] = *(const bf16x8*)(wbf + bbase +                     \
                                                 ((kc) * 4 + s) * 32);             \
        } else {                                                                   \
            const float* bp = w_in + bbase + ((kc) * 4 + s) * 32;                  \
            regB[(kc) & 1][s] = pack8(*(const float4*)bp, *(const float4*)(bp+4)); \
        }                                                                          \
    }

#define STOREC(kc, sv)                                                             \
    _Pragma("unroll")                                                              \
    for (int i = 0; i < 8; ++i) {                                                  \
        const int row = i * 8 + srow;                                              \
        bf16x4 v4;                                                                 \
        v4[0] = (short)f2bf(sv[i][0]); v4[1] = (short)f2bf(sv[i][1]);              \
        v4[2] = (short)f2bf(sv[i][2]); v4[3] = (short)f2bf(sv[i][3]);              \
        *(bf16x4*)&smem[((kc) & 1) * 8192 + row * 128 + (scol ^ sswz)] = v4;       \
    }

    // COMPUTE(kc): pure LDS + MFMA. A row-tiles rt=0..3 (rows rt*16+lr),
    // B from regB[kc&1] (this wave's 16 cols).
#define COMPUTE(kc)                                                                \
    {                                                                              \
        const int bb = ((kc) & 1) * 8192;                                          \
        _Pragma("unroll")                                                          \
        for (int s = 0; s < 4; ++s) {                                              \
            _Pragma("unroll")                                                      \
            for (int rt = 0; rt < 4; ++rt) {                                       \
                const int arow = rt * 16 + lr;                                     \
                bf16x8 af = *(const bf16x8*)&smem[bb + arow * 128 +                \
                                ((s * 32 + lg * 8) ^ ((arow & 7) << 3))];          \
                acc[rt] = __builtin_amdgcn_mfma_f32_16x16x32_bf16(                 \
                              af, regB[(kc) & 1][s], acc[rt], 0, 0, 0);            \
            }                                                                      \
        }                                                                          \
    }

// pin vmem issue order (B before next obs) without blocking VALU/SALU/DS motion
#define VMEM_FENCE() __builtin_amdgcn_sched_barrier(0x106)

// raw barrier: LDS-visibility only; does NOT drain vmcnt (T4 counted-vmcnt).
// lgkmcnt(0) completes this wave's ds_writes (visible after barrier) and its
// ds_reads (so the next iteration may overwrite the buffer it just read).
#define LDS_BARRIER() asm volatile("s_waitcnt lgkmcnt(0)\n\ts_barrier" ::: "memory")

    f32x4 acc[4];
    #pragma unroll
    for (int t = 0; t < 4; ++t) acc[t] = (f32x4){0.f, 0.f, 0.f, 0.f};

    // ---- layer 1 pipeline: 2-deep nt obs prefetch, vmem-free COMPUTE ----
    BLOAD(0)
    LOADC(0, svA)
    LOADC(1, svB)
    STOREC(0, svA)          // counted vmcnt: obs(1) stays in flight
    LDS_BARRIER();
    for (int kc = 1; kc < NCHUNK - 1; kc += 2) {    // kc = 1, 3, 5
        BLOAD(kc)
        VMEM_FENCE();
        LOADC(kc + 1, svA)                           // 2-ahead obs prefetch
        COMPUTE(kc - 1)                              // waits B(kc-1): long done
        STOREC(kc, svB)                              // waits obs(kc): ~1.5 iters old
        LDS_BARRIER();
        BLOAD(kc + 1)
        VMEM_FENCE();
        LOADC(kc + 2, svB)
        COMPUTE(kc)
        STOREC(kc + 1, svA)
        LDS_BARRIER();
    }
    BLOAD(NCHUNK - 1)
    COMPUTE(NCHUNK - 2)
    STOREC(NCHUNK - 1, svB)
    LDS_BARRIER();
    COMPUTE(NCHUNK - 1)
    __syncthreads();       // one-time full drain before LDS overlay re-use

    ushort* x_lds = smem;               // [64][72]
    ushort* z_lds = smem + 4608;        // [64][72]
    ushort* wdq   = smem + 9216;        // [64][72]
    ushort* wh    = smem + 13824;       // [16][72]

    // x = tanh(acc + b_in) -> x_lds[row][h]; this wave wrote cols w*16+lr
    {
        const float b = b_in[w * 16 + lr];
        #pragma unroll
        for (int rt = 0; rt < 4; ++rt)
            #pragma unroll
            for (int r = 0; r < 4; ++r)
                x_lds[(rt * 16 + lg * 4 + r) * 72 + w * 16 + lr] =
                    f2bf(fast_tanh(acc[rt][r] + b));
    }

    // ---- NVFP4 fake-quant dequant of w_h1 -> wdq bf16 ----
    {
        const int o  = tid >> 2;
        const int hb = tid & 3;
        const float* wp = w_h1 + o * HIDDEN + hb * 16;
        float v[16];
        #pragma unroll
        for (int i = 0; i < 4; ++i) {
            float4 t4 = *(const float4*)(wp + i * 4);
            v[i*4+0] = t4.x; v[i*4+1] = t4.y; v[i*4+2] = t4.z; v[i*4+3] = t4.w;
        }
        float amax = 0.f;
        #pragma unroll
        for (int i = 0; i < 16; ++i) amax = fmaxf(amax, fabsf(v[i]));
        float scale = amax / 6.0f;
        if (scale == 0.f) scale = 1.f;
        #pragma unroll
        for (int i = 0; i < 16; ++i) {
            float xq = v[i] / scale;
            float ax = fabsf(xq);
            float q;
            if      (ax <= 0.25f) q = 0.0f;
            else if (ax <= 0.75f) q = 0.5f;
            else if (ax <= 1.25f) q = 1.0f;
            else if (ax <= 1.75f) q = 1.5f;
            else if (ax <= 2.5f)  q = 2.0f;
            else if (ax <= 3.5f)  q = 3.0f;
            else if (ax <= 5.0f)  q = 4.0f;
            else                  q = 6.0f;
            q = (xq < 0.f) ? -q : q;
            wdq[o * 72 + hb * 16 + i] = f2bf(q * scale);
        }
    }
    // head weights -> wh
    for (int t2 = tid; t2 < 16 * 64; t2 += 256) {
        const int o = t2 >> 6, h = t2 & 63;
        float val = (o < 8) ? w_pi[o * HIDDEN + h] : (o == 8 ? w_v[h] : 0.0f);
        wh[o * 72 + h] = f2bf(val);
    }
    __syncthreads();

    // ---- layer 2: z = tanh(x @ wdq^T + b_h1), K=64 (per-wave row strip) ----
    f32x4 acc2[4];
    #pragma unroll
    for (int t = 0; t < 4; ++t) acc2[t] = (f32x4){0.f, 0.f, 0.f, 0.f};
    #pragma unroll
    for (int ks = 0; ks < 2; ++ks) {
        bf16x8 af = *(const bf16x8*)&x_lds[(w * 16 + lr) * 72 + ks * 32 + lg * 8];
        #pragma unroll
        for (int t = 0; t < 4; ++t) {
            bf16x8 bfr = *(const bf16x8*)&wdq[(t * 16 + lr) * 72 + ks * 32 + lg * 8];
            acc2[t] = __builtin_amdgcn_mfma_f32_16x16x32_bf16(af, bfr, acc2[t], 0, 0, 0);
        }
    }
    #pragma unroll
    for (int t = 0; t < 4; ++t) {
        const float b = b_h1[t * 16 + lr];
        #pragma unroll
        for (int r = 0; r < 4; ++r)
            z_lds[(w * 16 + lg * 4 + r) * 72 + t * 16 + lr] = f2bf(fast_tanh(acc2[t][r] + b));
    }
    __syncthreads();

    // ---- heads as one 16-col MFMA tile (cols 0-7 mean, 8 value) ----
    f32x4 acc3 = (f32x4){0.f, 0.f, 0.f, 0.f};
    #pragma unroll
    for (int ks = 0; ks < 2; ++ks) {
        bf16x8 af  = *(const bf16x8*)&z_lds[(w * 16 + lr) * 72 + ks * 32 + lg * 8];
        bf16x8 bfr = *(const bf16x8*)&wh[lr * 72 + ks * 32 + lg * 8];
        acc3 = __builtin_amdgcn_mfma_f32_16x16x32_bf16(af, bfr, acc3, 0, 0, 0);
    }
    #pragma unroll
    for (int r = 0; r < 4; ++r) {
        const int row = row0 + w * 16 + lg * 4 + r;
        if (lr < 8)
            out[(size_t)row * 8 + lr] = acc3[r] + b_pi[lr];
        else if (lr == 8)
            out[(size_t)2 * BATCH * 8 + row] = acc3[r] + b_v[0];
    }

    // ---- std broadcast ----
    {
        const int idx = tid * 2;
        const int rl = idx >> 3, a = idx & 7;
        float2 s;
        s.x = __expf(log_std[a]);
        s.y = __expf(log_std[a + 1]);
        *(float2*)&out[(size_t)BATCH * 8 + (size_t)(row0 + rl) * 8 + a] = s;
    }
#undef LOADC
#undef BLOAD
#undef STOREC
#undef COMPUTE
#undef VMEM_FENCE
#undef LDS_BARRIER
}

extern "C" void kernel_launch(void* const* d_in, const int* in_sizes, int n_in,
                              void* d_out, int out_size, void* d_ws, size_t ws_size,
                              hipStream_t stream) {
    (void)in_sizes; (void)n_in; (void)out_size;
    const float* obs   = (const float*)d_in[0];
    const float* w_in  = (const float*)d_in[1];
    const float* b_in  = (const float*)d_in[2];
    const float* w_h1  = (const float*)d_in[3];
    const float* b_h1  = (const float*)d_in[4];
    const float* w_pi  = (const float*)d_in[5];
    const float* b_pi  = (const float*)d_in[6];
    const float* w_v   = (const float*)d_in[7];
    const float* b_v   = (const float*)d_in[8];
    const float* lstd  = (const float*)d_in[9];
    float* out = (float*)d_out;

    const size_t wbf_bytes = (size_t)HIDDEN * OBS_DIM * sizeof(ushort);
    if (ws_size >= wbf_bytes) {
        ushort* wbf = (ushort*)d_ws;
        hipLaunchKernelGGL(w_in_to_bf16, dim3(HIDDEN * OBS_DIM / 1024), dim3(256), 0, stream,
                           w_in, wbf);
        hipLaunchKernelGGL((ac_mfma<true>), dim3(NBLOCKS), dim3(256), 0, stream,
                           obs, w_in, b_in, w_h1, b_h1, w_pi, b_pi, w_v, b_v, lstd,
                           wbf, out);
    } else {
        hipLaunchKernelGGL((ac_mfma<false>), dim3(NBLOCKS), dim3(256), 0, stream,
                           obs, w_in, b_in, w_h1, b_h1, w_pi, b_pi, w_v, b_v, lstd,
                           (const ushort*)nullptr, out);
    }
}